// Round 3
// baseline (1162.287 us; speedup 1.0000x reference)
//
#include <hip/hip_runtime.h>
#include <stdint.h>

// B=1024, L=86 -> M = 88064 rows, D=512, NV=8 heads, DV=64. TM=32 rows/block.
#define DD 512
#define TM 32
#define NBLK 2752   // 88064/32, exact (no tail)

using f32x4 = __attribute__((ext_vector_type(4))) float;
using s16x8 = __attribute__((ext_vector_type(8))) short;
using s16x4 = __attribute__((ext_vector_type(4))) short;
typedef unsigned short u16;

static __device__ __forceinline__ u16 f2bf(float f) {
    uint32_t u = __builtin_bit_cast(uint32_t, f);
    uint32_t r = u + 0x7fffu + ((u >> 16) & 1u);   // round-to-nearest-even
    return (u16)(r >> 16);
}

// ---------------- weight prep: Wt[n][k] = bf16(W[k][n]) ----------------
__global__ __launch_bounds__(256) void prep_weights(
    const float* __restrict__ W0, const float* __restrict__ W1,
    const float* __restrict__ W2, const float* __restrict__ W3,
    u16* __restrict__ out)
{
    __shared__ float tile[32][33];
    const int mat = blockIdx.z;
    const float* W = mat == 0 ? W0 : mat == 1 ? W1 : mat == 2 ? W2 : W3;
    u16* o = out + (size_t)mat * DD * DD;
    const int tx = threadIdx.x & 31, ty = threadIdx.x >> 5;   // 32 x 8
    const int k0 = blockIdx.y * 32, n0 = blockIdx.x * 32;
#pragma unroll
    for (int s = 0; s < 32; s += 8)
        tile[ty + s][tx] = W[(size_t)(k0 + ty + s) * DD + n0 + tx];
    __syncthreads();
#pragma unroll
    for (int s = 0; s < 32; s += 8)
        o[(size_t)(n0 + ty + s) * DD + k0 + tx] = f2bf(tile[tx][ty + s]);
}

// ---------------- fused main kernel ----------------
// LDS tiles are [32][512] bf16, byte-swizzled: elem (row,k) at byte row*1024 + ((2k) ^ ((row&7)<<4))

static __device__ __forceinline__ void stage_tile(u16* __restrict__ s,
                                                  const float* __restrict__ g,
                                                  int r0, int tid)
{
    const float4* gp = (const float4*)(g + (size_t)r0 * DD);
#pragma unroll
    for (int it = 0; it < 8; ++it) {
        int f = tid + it * 512;          // float4 index 0..4095 (linear, coalesced)
        int row = f >> 7;                // /128 float4s per row
        int fi = f & 127;
        float4 v = gp[f];
        s16x4 h;
        h[0] = (short)f2bf(v.x); h[1] = (short)f2bf(v.y);
        h[2] = (short)f2bf(v.z); h[3] = (short)f2bf(v.w);
        int byte = (row << 10) + (((fi << 3)) ^ ((row & 7) << 4));
        *(s16x4*)((char*)s + byte) = h;
    }
}

// MODE 0: ->sOut std order (bias bq); 1: ->sOut std (bk); 2: ->sOut head-permuted (bv); 3: ->global f32 (bfc)
template <int MODE>
static __device__ __forceinline__ void do_gemm(const u16* __restrict__ sIn,
                                               const u16* __restrict__ Wg,
                                               const float* __restrict__ bias,
                                               u16* __restrict__ sOut,
                                               float* __restrict__ gOut,
                                               int r0, int lane, int wv)
{
    f32x4 acc[2][4] = {};
    const int lr = lane & 15;
    const int lg = lane >> 4;
    const int sw0 = (lr & 7) << 4;        // same swizzle for rows lr and lr+16
    // B (weights) straight from global/L2: col c = wv*64 + ni*16 + lr, k = kk*32 + lg*8 + e
    const u16* bptr = Wg + ((size_t)(wv * 64 + lr)) * DD + (lg << 3);
#pragma unroll
    for (int kk = 0; kk < 16; ++kk) {
        const int kb = (kk << 6) + (lg << 4);
        s16x8 a0 = *(const s16x8*)((const char*)sIn + ((lr) << 10) + (kb ^ sw0));
        s16x8 a1 = *(const s16x8*)((const char*)sIn + ((16 + lr) << 10) + (kb ^ sw0));
#pragma unroll
        for (int ni = 0; ni < 4; ++ni) {
            s16x8 b = *(const s16x8*)(bptr + (ni << 13) + (kk << 5));
            acc[0][ni] = __builtin_amdgcn_mfma_f32_16x16x32_bf16(a0, b, acc[0][ni], 0, 0, 0);
            acc[1][ni] = __builtin_amdgcn_mfma_f32_16x16x32_bf16(a1, b, acc[1][ni], 0, 0, 0);
        }
    }
#pragma unroll
    for (int mi = 0; mi < 2; ++mi) {
#pragma unroll
        for (int ni = 0; ni < 4; ++ni) {
            const int c = wv * 64 + ni * 16 + lr;
            const float bi = bias[c];
#pragma unroll
            for (int r = 0; r < 4; ++r) {
                const int row = mi * 16 + lg * 4 + r;   // D: col=lane&15, row=4*(lane>>4)+reg (m89)
                float v = fmaxf(acc[mi][ni][r] + bi, 0.f);
                if (MODE == 3) {
                    gOut[(size_t)(r0 + row) * DD + c] = v;
                } else if (MODE == 2) {
                    // permuted store for PV: col' = dv*8 + head, head = wv
                    const int dv = c & 63;
                    const int byte = (row << 10) + ((((dv << 3) + wv) << 1) ^ ((row & 7) << 4));
                    *(u16*)((char*)sOut + byte) = f2bf(v);
                } else {
                    const int byte = (row << 10) + ((c << 1) ^ ((row & 7) << 4));
                    *(u16*)((char*)sOut + byte) = f2bf(v);
                }
            }
        }
    }
}

// scores + softmax for the wave's 4 rows (2 row-pairs packed per MFMA); writes normalized P (bf16) to sP
static __device__ __forceinline__ void scores_softmax(const u16* __restrict__ sQ,
                                                      const u16* __restrict__ sK,
                                                      u16* __restrict__ sP,
                                                      int lane, int wv)
{
    const int lr = lane & 15, lg = lane >> 4;
    const int nm = lr & 7;      // head index (n for A-role / m for B-role)
    const int ph = lr >> 3;     // which row of the pair
#pragma unroll
    for (int pp = 0; pp < 2; ++pp) {
        const int row = wv * 4 + pp * 2 + ph;
        const int rb = row << 10;
        const int sw = (row & 7) << 4;
        f32x4 sc = {};
#pragma unroll
        for (int kk = 0; kk < 2; ++kk) {
            const int off = ((nm << 7) + (kk << 6) + (lg << 4)) ^ sw;
            s16x8 aq = *(const s16x8*)((const char*)sQ + rb + off);
            s16x8 bk = *(const s16x8*)((const char*)sK + rb + off);
            sc = __builtin_amdgcn_mfma_f32_16x16x32_bf16(aq, bk, sc, 0, 0, 0);
        }
        float pn[4];
#pragma unroll
        for (int r = 0; r < 4; ++r) {
            float s = sc[r];
            float mx = s;
            mx = fmaxf(mx, __shfl_xor(mx, 1));
            mx = fmaxf(mx, __shfl_xor(mx, 2));
            mx = fmaxf(mx, __shfl_xor(mx, 4));
            float e = __expf((s - mx) * 0.125f);    // scale 1/sqrt(64)
            float sm = e;
            sm += __shfl_xor(sm, 1);
            sm += __shfl_xor(sm, 2);
            sm += __shfl_xor(sm, 4);
            pn[r] = e / sm;
        }
        if ((lg >> 1) == ph) {                      // valid block-diagonal lanes only
            const int p = ph, m = nm;
#pragma unroll
            for (int r = 0; r < 4; ++r) {
                const int a = p * 8 + (lg & 1) * 4 + r;
                sP[wv * 1024 + pp * 512 + a * 32 + p * 8 + m] = f2bf(pn[r]);
            }
        }
    }
}

// ctx = P @ V (head-permuted sV), + residual query, -> swizzled out-tile (sO)
static __device__ __forceinline__ void pv_residual(const u16* __restrict__ sP,
                                                   const u16* __restrict__ sV,
                                                   u16* __restrict__ sO,
                                                   const float* __restrict__ q_in,
                                                   int r0, int lane, int wv)
{
    const int lr = lane & 15, lg = lane >> 4;
#pragma unroll
    for (int pp = 0; pp < 2; ++pp) {
        s16x8 ap = *(const s16x8*)&sP[wv * 1024 + pp * 512 + lr * 32 + lg * 8];
        const int rowb = wv * 4 + pp * 2 + (lg & 1);    // lg>=2 reads are killed by zero P
        const int rbb = rowb << 10;
        const int swb = (rowb & 7) << 4;
        f32x4 ctx[4];
#pragma unroll
        for (int ndv = 0; ndv < 4; ++ndv) {
            const int dv = ndv * 16 + lr;
            s16x8 bv = *(const s16x8*)((const char*)sV + rbb + ((dv << 4) ^ swb));
            f32x4 z = {0.f, 0.f, 0.f, 0.f};
            ctx[ndv] = __builtin_amdgcn_mfma_f32_16x16x32_bf16(ap, bv, z, 0, 0, 0);
        }
#pragma unroll
        for (int ndv = 0; ndv < 4; ++ndv) {
#pragma unroll
            for (int r = 0; r < 4; ++r) {
                const int drow = lg * 4 + r;
                const int p = drow >> 3, n = drow & 7;
                const int row = wv * 4 + pp * 2 + p;
                const int dv = ndv * 16 + lr;
                const int col = n * 64 + dv;
                float v = ctx[ndv][r] + q_in[(size_t)(r0 + row) * DD + col];
                const int byte = (row << 10) + ((col << 1) ^ ((row & 7) << 4));
                *(u16*)((char*)sO + byte) = f2bf(v);
            }
        }
    }
}

__global__ __launch_bounds__(512, 2) void fused_attn(
    const float* __restrict__ q_in, const float* __restrict__ k_in,
    const float* __restrict__ v_in,
    const float* __restrict__ bq, const float* __restrict__ bk,
    const float* __restrict__ bv, const float* __restrict__ bfc,
    const u16* __restrict__ Wt, float* __restrict__ out)
{
    __shared__ u16 sA[TM * DD];   // input tile (query/key/value, staged per projection)
    __shared__ u16 sQ[TM * DD];   // q2, later v2 (head-permuted)
    __shared__ u16 sK[TM * DD];   // k2, later out-tile (ctx+residual)
    __shared__ u16 sP[8 * 1024];  // per-wave P: 2 pairs x 16x32 bf16, zero-padded

    const int tid = threadIdx.x;
    const int lane = tid & 63;
    const int wv = tid >> 6;
    const int r0 = blockIdx.x * TM;

    const u16* WtQ = Wt;
    const u16* WtK = Wt + DD * DD;
    const u16* WtV = Wt + 2 * DD * DD;
    const u16* WtF = Wt + 3 * DD * DD;

    {   // zero P buffer (off-diagonal k-blocks must be 0 for exact PV)
        s16x8 zz = {};
        *(s16x8*)&sP[tid * 8] = zz;
        *(s16x8*)&sP[tid * 8 + 4096] = zz;
    }

    stage_tile(sA, q_in, r0, tid);
    __syncthreads();
    do_gemm<0>(sA, WtQ, bq, sQ, nullptr, r0, lane, wv);     // q2 -> sQ
    __syncthreads();
    stage_tile(sA, k_in, r0, tid);
    __syncthreads();
    do_gemm<1>(sA, WtK, bk, sK, nullptr, r0, lane, wv);     // k2 -> sK
    __syncthreads();
    stage_tile(sA, v_in, r0, tid);                          // overlaps with scores
    scores_softmax(sQ, sK, sP, lane, wv);                   // per-wave rows only
    __syncthreads();
    do_gemm<2>(sA, WtV, bv, sQ, nullptr, r0, lane, wv);     // v2 -> sQ (permuted)
    __syncthreads();
    pv_residual(sP, sQ, sK, q_in, r0, lane, wv);            // out-tile -> sK
    __syncthreads();
    do_gemm<3>(sK, WtF, bfc, nullptr, out, r0, lane, wv);   // relu(out@Wfc+bfc) -> HBM
}

extern "C" void kernel_launch(void* const* d_in, const int* in_sizes, int n_in,
                              void* d_out, int out_size, void* d_ws, size_t ws_size,
                              hipStream_t stream)
{
    const float* q   = (const float*)d_in[0];
    const float* k   = (const float*)d_in[1];
    const float* v   = (const float*)d_in[2];
    const float* Wq  = (const float*)d_in[3];
    const float* bq  = (const float*)d_in[4];
    const float* Wk  = (const float*)d_in[5];
    const float* bk  = (const float*)d_in[6];
    const float* Wv  = (const float*)d_in[7];
    const float* bv  = (const float*)d_in[8];
    const float* Wfc = (const float*)d_in[9];
    const float* bfc = (const float*)d_in[10];
    u16* Wt = (u16*)d_ws;   // 4 x 512x512 bf16 = 2 MB

    dim3 pgrid(16, 16, 4);
    prep_weights<<<pgrid, 256, 0, stream>>>(Wq, Wk, Wv, Wfc, Wt);
    fused_attn<<<NBLK, 512, 0, stream>>>(q, k, v, bq, bk, bv, bfc, Wt, (float*)d_out);
}